// Round 2
// baseline (365.531 us; speedup 1.0000x reference)
//
#include <hip/hip_runtime.h>
#include <stdint.h>

typedef float    f32x4 __attribute__((ext_vector_type(4)));
typedef _Float16 f16x8 __attribute__((ext_vector_type(8)));
typedef unsigned int u32x4 __attribute__((ext_vector_type(4)));

#define NN     4096
#define KTOT   12288     // 3*4096 stacked k-rows
#define CDIM   384       // B*F_OUT*T = 2*16*12
#define BN     128
#define BK     32
#define TSTEPS 384       // KTOT / BK

// ---------------------------------------------------------------------------
// Kernel 1: z builder.  z[c][m'] (fp16), c = b*192 + o*12 + t, m' = k*4096+m
// z[k,b,m,o,t] = sum_f x[b,m,f,t] * lhs[k,f,o];  lhs = sum_j Gamma_j * xj[j,k]
// grid: 256 blocks = (b in {0,1}) x (128 m-tiles of 32), 256 threads
// ---------------------------------------------------------------------------
__global__ __launch_bounds__(256) void zbuild_kernel(
    const float* __restrict__ x,      // (2,4096,16,12)
    const float* __restrict__ xj,     // (3,3)  [j][k]
    const float* __restrict__ gamma,  // (3,16,16) [j][f][o]
    _Float16* __restrict__ zws)       // (384, 12288)
{
  __shared__ float xs[32 * 193];   // x tile, padded row 193 (bank-spread)
  __shared__ float lhs[768];       // [k][f][o]
  const int tid = threadIdx.x;
  const int b   = blockIdx.x & 1;
  const int m0  = (blockIdx.x >> 1) << 5;

  // lhs[k*256 + f*16 + o] = sum_j Gamma[j,f,o] * xj[j,k]
  for (int e = tid; e < 768; e += 256) {
    const int k = e >> 8, fo = e & 255;
    float s = 0.f;
#pragma unroll
    for (int j = 0; j < 3; ++j) s += gamma[j * 256 + fo] * xj[j * 3 + k];
    lhs[e] = s;
  }
  // stage x[b][m0..m0+32][*][*] : 32 rows x 192 floats, coalesced float4
  const float* xsrc = x + (size_t)(b * 4096 + m0) * 192;
  for (int q = tid; q < 1536; q += 256) {
    const int fl  = q << 2;
    const int ml  = fl / 192;
    const int off = fl - ml * 192;
    const f32x4 v = *(const f32x4*)(xsrc + fl);
#pragma unroll
    for (int r = 0; r < 4; ++r) xs[ml * 193 + off + r] = v[r];
  }
  __syncthreads();

  for (int slot = tid; slot < 512; slot += 256) {
    const int ml = slot & 31, o = slot >> 5;
    float acc[3][12];
#pragma unroll
    for (int k = 0; k < 3; ++k)
#pragma unroll
      for (int t = 0; t < 12; ++t) acc[k][t] = 0.f;

#pragma unroll
    for (int f = 0; f < 16; ++f) {
      float xv[12];
#pragma unroll
      for (int t = 0; t < 12; ++t) xv[t] = xs[ml * 193 + f * 12 + t];
#pragma unroll
      for (int k = 0; k < 3; ++k) {
        const float lf = lhs[k * 256 + f * 16 + o];
#pragma unroll
        for (int t = 0; t < 12; ++t) acc[k][t] += xv[t] * lf;
      }
    }
    const int mg = m0 + ml;
    const int cb = b * 192 + o * 12;
#pragma unroll
    for (int k = 0; k < 3; ++k)
#pragma unroll
      for (int t = 0; t < 12; ++t)
        zws[(size_t)(cb + t) * KTOT + k * 4096 + mg] = (_Float16)acc[k][t];
  }
}

// ---------------------------------------------------------------------------
// Kernel 2: GEMM  OutT[c][n] = sum_m' z[c][m'] * cheb[m'][n]   (fp16 MFMA)
// block: 384c x 128n tile, BK=32, 512 thr (8 waves: 4c x 2n, wave 96x64)
// split-K: by = blockIdx.x % S  (S=8 = #XCDs; blockIdx%8 is the XCD id under
//          default round-robin dispatch -> each k-chunk's 1.2MB z panel is
//          read 32x from ONE XCD's L2, not from HBM)
// LDS 64KB double-buffered.
//   As [c][32] fp16, 16B-block XOR swizzle: blk = (c*4+q) ^ ((c>>1)&3)
//     (without it: 64B pitch -> banks repeat every 2 rows -> 8-way conflict
//      on the 6 MFMA b128 A-reads; with it: 2-way = free per m136)
//   Bs [n][32] fp16 (chebT), blk = (n*4+q) ^ ((n>>2)&7)  (same reasoning)
// ---------------------------------------------------------------------------
__global__ __launch_bounds__(512, 2) void gemm_kernel(
    const float* __restrict__ cheb,     // (12288, 4096)
    const _Float16* __restrict__ zws,   // (384, 12288)
    float* __restrict__ partials,       // (S, 384, 4096)
    int S, int spb)
{
  __shared__ unsigned short As[2][CDIM * BK];   // 24576 B each
  __shared__ unsigned short Bs[2][BN * BK];     //  8192 B each

  const int tid  = threadIdx.x;
  const int by   = blockIdx.x % S;     // k-chunk (== XCD id when S==8)
  const int bx   = blockIdx.x / S;     // n-block
  const int lane = tid & 63, wid = tid >> 6;
  const int l15  = lane & 15, l4 = lane >> 4;
  const int wc   = wid >> 1, wn = wid & 1;
  const int nbase = bx * BN;
  const int step0 = by * spb;
  int nsteps = TSTEPS - step0;
  if (nsteps > spb) nsteps = spb;
  if (nsteps < 0) nsteps = 0;

  f32x4 acc[6][4];
#pragma unroll
  for (int mi = 0; mi < 6; ++mi)
#pragma unroll
    for (int ni = 0; ni < 4; ++ni) acc[mi][ni] = (f32x4)(0.f);

  const int ia0 = wid * 192 + lane;        // A staging chunk base (3 chunks)
  const int rrB = tid >> 5;                // B staging: row-pair index
  const int n4B = (tid & 31) << 2;         // B staging: 4 consecutive n

  u32x4 areg[3];
  f32x4 breg[2];

  auto LOADA = [&](int t) {
    const size_t mb = (size_t)(step0 + t) * (BK * 2);  // byte offset of m0g*2
#pragma unroll
    for (int j = 0; j < 3; ++j) {
      const int i = ia0 + j * 64;          // i = c*4 + q  (q = 8-fp16 quarter)
      const char* p = (const char*)zws + (size_t)(i >> 2) * (KTOT * 2) + mb + (i & 3) * 16;
      areg[j] = *(const u32x4*)p;
    }
  };
  auto LOADB = [&](int t) {
    const int m0g = (step0 + t) * BK;
#pragma unroll
    for (int s = 0; s < 2; ++s) {
      const int m = rrB * 2 + s;
      breg[s] = *(const f32x4*)(cheb + (size_t)(m0g + m) * NN + nbase + n4B);
    }
  };
  auto WRITEA = [&](int buf) {
#pragma unroll
    for (int j = 0; j < 3; ++j) {
      const int i   = ia0 + j * 64;
      const int c   = i >> 2;
      const int blk = i ^ ((c >> 1) & 3);   // XOR swizzle (bijective per row)
      *(u32x4*)&As[buf][blk * 8] = areg[j];
    }
  };
  auto WRITEB = [&](int buf) {
#pragma unroll
    for (int d = 0; d < 4; ++d) {
      const _Float16 h0 = (_Float16)breg[0][d];   // row 2*rrB
      const _Float16 h1 = (_Float16)breg[1][d];   // row 2*rrB+1 (adjacent m)
      const int n   = n4B + d;
      const int us0 = n * BK + rrB * 2;           // [n][m] fp16 index (even)
      int blk = us0 >> 3;
      blk ^= (n >> 2) & 7;                        // 16B-block XOR swizzle
      const int usp = blk * 8 + (us0 & 7);
      const uint32_t w = (uint32_t)__builtin_bit_cast(unsigned short, h0) |
                         ((uint32_t)__builtin_bit_cast(unsigned short, h1) << 16);
      *(uint32_t*)&Bs[buf][usp] = w;
    }
  };
  auto COMPUTE = [&](int cur) {
    f16x8 af[6];
#pragma unroll
    for (int mi = 0; mi < 6; ++mi) {
      const int c   = wc * 96 + mi * 16 + l15;
      const int i   = c * 4 + l4;
      const int blk = i ^ ((c >> 1) & 3);
      af[mi] = *(const f16x8*)&As[cur][blk * 8];             // ds_read_b128
    }
    f16x8 bf[4];
#pragma unroll
    for (int ni = 0; ni < 4; ++ni) {
      const int n   = wn * 64 + ni * 16 + l15;
      const int blk = (n * 4 + l4) ^ ((n >> 2) & 7);
      bf[ni] = *(const f16x8*)&Bs[cur][blk * 8];             // ds_read_b128
    }
#pragma unroll
    for (int mi = 0; mi < 6; ++mi)
#pragma unroll
      for (int ni = 0; ni < 4; ++ni)
        acc[mi][ni] = __builtin_amdgcn_mfma_f32_16x16x32_f16(
            af[mi], bf[ni], acc[mi][ni], 0, 0, 0);
  };

  if (nsteps > 0) {
    LOADA(0); LOADB(0);
    WRITEA(0); WRITEB(0);
    __syncthreads();
    for (int t = 0; t < nsteps; ++t) {
      const int cur = t & 1;
      const bool pf = (t + 1 < nsteps);
      if (pf) { LOADA(t + 1); LOADB(t + 1); }   // issue early (hide under MFMA)
      COMPUTE(cur);
      if (pf) { WRITEA(cur ^ 1); WRITEB(cur ^ 1); }
      __syncthreads();                           // drains vm+lgkm, swaps buffers
    }
  }

  // epilogue: partials[by][c][n]  (C/D frag: col=lane&15, row=(lane>>4)*4+r)
  float* pb = partials + (size_t)by * ((size_t)CDIM * NN);
#pragma unroll
  for (int mi = 0; mi < 6; ++mi) {
    const int c0 = wc * 96 + mi * 16 + l4 * 4;
#pragma unroll
    for (int ni = 0; ni < 4; ++ni) {
      const int n = nbase + wn * 64 + ni * 16 + l15;
#pragma unroll
      for (int r = 0; r < 4; ++r)
        pb[(size_t)(c0 + r) * NN + n] = acc[mi][ni][r];
    }
  }
}

// ---------------------------------------------------------------------------
// Kernel 3: sum S partial slabs, 0.5*relu, transpose c<->n via LDS,
// write out[b][n][o][t] coalesced.  grid (128 n-tiles of 32, 2 b-chunks)
// ---------------------------------------------------------------------------
__global__ __launch_bounds__(256) void reduce_kernel(
    const float* __restrict__ partials, float* __restrict__ out, int S)
{
  __shared__ float T[192 * 33];
  const int tid = threadIdx.x;
  const int n0  = blockIdx.x * 32;
  const int cb  = blockIdx.y;          // batch chunk: c in [cb*192, cb*192+192)

  for (int i = tid; i < 6144; i += 256) {
    const int c_l = i >> 5, n_l = i & 31;
    const float* p = partials + (size_t)(cb * 192 + c_l) * NN + n0 + n_l;
    float s = 0.f;
    for (int ss = 0; ss < S; ++ss) s += p[(size_t)ss * ((size_t)CDIM * NN)];
    T[c_l * 33 + n_l] = s;
  }
  __syncthreads();
  for (int j = tid; j < 6144; j += 256) {
    const int n_l = j / 192, ot = j - n_l * 192;
    const float v = 0.5f * T[ot * 33 + n_l];   // 2/(K+1) = 0.5
    out[(size_t)(cb * 4096 + n0 + n_l) * 192 + ot] = v > 0.f ? v : 0.f;
  }
}

// ---------------------------------------------------------------------------
extern "C" void kernel_launch(void* const* d_in, const int* in_sizes, int n_in,
                              void* d_out, int out_size, void* d_ws, size_t ws_size,
                              hipStream_t stream) {
  (void)in_sizes; (void)n_in; (void)out_size;
  const float* x     = (const float*)d_in[0];
  const float* cheb  = (const float*)d_in[1];
  const float* xj    = (const float*)d_in[2];
  const float* gamma = (const float*)d_in[3];
  float* out = (float*)d_out;

  const long long zbytes = (long long)CDIM * KTOT * 2;   // 9,437,184
  const long long pslab  = (long long)CDIM * NN * 4;     // 6,291,456
  int S = 8;
  const long long avail = (long long)ws_size - zbytes;
  if (avail < 8 * pslab) {
    S = (int)(avail / pslab);
    if (S < 1) S = 1;
    if (S > 8) S = 8;
  }
  const int spb = (TSTEPS + S - 1) / S;

  _Float16* zws   = (_Float16*)d_ws;
  float* partials = (float*)((char*)d_ws + zbytes);

  zbuild_kernel<<<256, 256, 0, stream>>>(x, xj, gamma, zws);
  gemm_kernel<<<32 * S, 512, 0, stream>>>(cheb, zws, partials, S, spb);
  reduce_kernel<<<dim3(128, 2), 256, 0, stream>>>(partials, out, S);
}